// Round 2
// baseline (770.154 us; speedup 1.0000x reference)
//
#include <hip/hip_runtime.h>
#include <hip/hip_bf16.h>

typedef __attribute__((ext_vector_type(8))) short short8;
typedef __attribute__((ext_vector_type(4))) float f32x4;

#define AS1 __attribute__((address_space(1)))
#define AS3 __attribute__((address_space(3)))

static __device__ __forceinline__ short f2bf(float f) {
    __hip_bfloat16 h = __float2bfloat16(f);
    union { __hip_bfloat16 h; short s; } u;
    u.h = h;
    return u.s;
}

// ---------------- prepack kernels (run every launch; deterministic) ----------------

// W: [N, K] int32 codes (0..255), dequant (q-128)*scale, scale per 32-K block.
// Writes bf16 row-major [N, K].
__global__ __launch_bounds__(256) void prepack_w_kernel(const int* __restrict__ wq,
                                                        const float* __restrict__ scales,
                                                        short* __restrict__ Wb,
                                                        long total8) {
    long i = (long)blockIdx.x * 256 + threadIdx.x;
    if (i >= total8) return;
    const int4* p = (const int4*)wq + i * 2;
    int4 q0 = p[0], q1 = p[1];
    float s = scales[(i * 8) >> 5];   // flat (n*K+k)/32 == n*(K/32)+k/32 since K%32==0
    short8 v;
    v[0] = f2bf((float)(q0.x - 128) * s);
    v[1] = f2bf((float)(q0.y - 128) * s);
    v[2] = f2bf((float)(q0.z - 128) * s);
    v[3] = f2bf((float)(q0.w - 128) * s);
    v[4] = f2bf((float)(q1.x - 128) * s);
    v[5] = f2bf((float)(q1.y - 128) * s);
    v[6] = f2bf((float)(q1.z - 128) * s);
    v[7] = f2bf((float)(q1.w - 128) * s);
    ((short8*)Wb)[i] = v;
}

__global__ __launch_bounds__(256) void prepack_x_kernel(const float* __restrict__ x,
                                                        short* __restrict__ Xb,
                                                        long total8) {
    long i = (long)blockIdx.x * 256 + threadIdx.x;
    if (i >= total8) return;
    const float4* p = (const float4*)x + i * 2;
    float4 f0 = p[0], f1 = p[1];
    short8 v;
    v[0] = f2bf(f0.x); v[1] = f2bf(f0.y); v[2] = f2bf(f0.z); v[3] = f2bf(f0.w);
    v[4] = f2bf(f1.x); v[5] = f2bf(f1.y); v[6] = f2bf(f1.z); v[7] = f2bf(f1.w);
    ((short8*)Xb)[i] = v;
}

// ---------------- GEMM: out[m][n] = sum_k x[m,k]*w[n,k] + bias[n] ----------------
// 128x128 tile, BK=64, 256 threads = 4 waves (2x2 of 64x64), mfma_f32_16x16x32_bf16.
// LDS layout: [row][granule] with granule = 16B (8 bf16); XOR swizzle sg = g ^ (row&7).
// PRE paths stage via global_load_lds (linear LDS dest, pre-swizzled global source).

template <bool PRE_A, bool PRE_B>
__global__ __launch_bounds__(256, 2)
void gemm_kernel(const float* __restrict__ x, const int* __restrict__ wq,
                 const float* __restrict__ scales, const float* __restrict__ bias,
                 const short* __restrict__ Xb, const short* __restrict__ Wb,
                 float* __restrict__ out, int M, int N, int K) {
    constexpr int BM = 128, BN = 128, BK = 64;
    __shared__ alignas(16) short As[BM * BK];
    __shared__ alignas(16) short Bs[BN * BK];

    const int nM = M / BM, nN = N / BN;
    int bid = blockIdx.x;
    int pm, pn;
    const int G = 8;  // n-panels per group: concurrent set = 32 m-panels x 8 n-panels (LLC-fit)
    if ((nN % G) == 0) {
        int per = nM * G;
        int grp = bid / per;
        int in  = bid % per;
        pn = grp * G + (in % G);
        pm = in / G;
    } else {
        pn = bid % nN;
        pm = bid / nN;
    }

    const int tid  = threadIdx.x;
    const int lane = tid & 63;
    const int wv   = tid >> 6;
    const int wm   = (wv >> 1) * 64;
    const int wn   = (wv & 1) * 64;
    const int q    = lane >> 4;   // 0..3
    const int l15  = lane & 15;
    const int sxor = lane & 7;    // row&7 for fragment rows (wm, mi*16 are 0 mod 8)

    const long bm = (long)pm * BM, bn = (long)pn * BN;

    f32x4 acc[4][4];
#pragma unroll
    for (int i = 0; i < 4; ++i)
#pragma unroll
        for (int j = 0; j < 4; ++j) acc[i][j] = (f32x4){0.f, 0.f, 0.f, 0.f};

    // fused-path staging mapping: 4 iters, row = it*32 + tid/8, granule = tid&7
    const int srow = tid >> 3;
    const int scg  = tid & 7;

    // fragment LDS offsets (in shorts): addr = row*64 + sg*8, sg = (kk*4+q) ^ sxor
    const int sg0   = q ^ sxor;
    const int aOff0 = (wm + l15) * 64 + sg0 * 8;
    const int aOff1 = (wm + l15) * 64 + (sg0 ^ 4) * 8;
    const int bOff0 = (wn + l15) * 64 + sg0 * 8;
    const int bOff1 = (wn + l15) * 64 + (sg0 ^ 4) * 8;

    // prepacked staging: per wave, rows [wv*32, wv*32+32); issue i covers 8 rows;
    // lane -> (row_rel = lane>>3, slot = lane&7); global granule = slot ^ (row&7)
    const int prRow  = lane >> 3;
    const int prGsrc = (lane & 7) ^ (lane >> 3);

    for (int k0 = 0; k0 < K; k0 += BK) {
        // ---- stage A ----
        if constexpr (PRE_A) {
#pragma unroll
            for (int i = 0; i < 4; ++i) {
                int r = wv * 32 + i * 8 + prRow;
                const short* src = Xb + (bm + r) * (long)K + k0 + prGsrc * 8;
                __builtin_amdgcn_global_load_lds((const AS1 void*)src,
                                                 (AS3 void*)&As[(wv * 32 + i * 8) * 64],
                                                 16, 0, 0);
            }
        } else {
#pragma unroll
            for (int i = 0; i < 4; ++i) {
                int r = i * 32 + srow;
                const float4* p = (const float4*)(x + (bm + r) * (long)K + k0 + scg * 8);
                float4 f0 = p[0], f1 = p[1];
                short8 v;
                v[0] = f2bf(f0.x); v[1] = f2bf(f0.y); v[2] = f2bf(f0.z); v[3] = f2bf(f0.w);
                v[4] = f2bf(f1.x); v[5] = f2bf(f1.y); v[6] = f2bf(f1.z); v[7] = f2bf(f1.w);
                int sg = scg ^ (r & 7);
                *(short8*)&As[r * 64 + sg * 8] = v;
            }
        }
        // ---- stage B ----
        if constexpr (PRE_B) {
#pragma unroll
            for (int i = 0; i < 4; ++i) {
                int r = wv * 32 + i * 8 + prRow;
                const short* src = Wb + (bn + r) * (long)K + k0 + prGsrc * 8;
                __builtin_amdgcn_global_load_lds((const AS1 void*)src,
                                                 (AS3 void*)&Bs[(wv * 32 + i * 8) * 64],
                                                 16, 0, 0);
            }
        } else {
#pragma unroll
            for (int i = 0; i < 4; ++i) {
                int r = i * 32 + srow;
                const int4* p = (const int4*)(wq + (bn + r) * (long)K + k0 + scg * 8);
                int4 q0 = p[0], q1 = p[1];
                float s = scales[(bn + r) * (long)(K >> 5) + ((k0 + scg * 8) >> 5)];
                short8 v;
                v[0] = f2bf((float)(q0.x - 128) * s);
                v[1] = f2bf((float)(q0.y - 128) * s);
                v[2] = f2bf((float)(q0.z - 128) * s);
                v[3] = f2bf((float)(q0.w - 128) * s);
                v[4] = f2bf((float)(q1.x - 128) * s);
                v[5] = f2bf((float)(q1.y - 128) * s);
                v[6] = f2bf((float)(q1.z - 128) * s);
                v[7] = f2bf((float)(q1.w - 128) * s);
                int sg = scg ^ (r & 7);
                *(short8*)&Bs[r * 64 + sg * 8] = v;
            }
        }
        __syncthreads();

#pragma unroll
        for (int kk = 0; kk < 2; ++kk) {
            short8 a[4], b[4];
            const int aBase = kk ? aOff1 : aOff0;
            const int bBase = kk ? bOff1 : bOff0;
#pragma unroll
            for (int mi = 0; mi < 4; ++mi) a[mi] = *(const short8*)&As[aBase + mi * 16 * 64];
#pragma unroll
            for (int nj = 0; nj < 4; ++nj) b[nj] = *(const short8*)&Bs[bBase + nj * 16 * 64];
#pragma unroll
            for (int mi = 0; mi < 4; ++mi)
#pragma unroll
                for (int nj = 0; nj < 4; ++nj)
                    acc[mi][nj] = __builtin_amdgcn_mfma_f32_16x16x32_bf16(
                        a[mi], b[nj], acc[mi][nj], 0, 0, 0);
        }
        __syncthreads();
    }

    // epilogue: C/D layout col = lane&15, row = (lane>>4)*4 + reg
#pragma unroll
    for (int nj = 0; nj < 4; ++nj) {
        long col = bn + wn + nj * 16 + l15;
        float bv = bias[col];
#pragma unroll
        for (int mi = 0; mi < 4; ++mi) {
            long row = bm + wm + mi * 16 + q * 4;
#pragma unroll
            for (int r2 = 0; r2 < 4; ++r2)
                out[(row + r2) * (long)N + col] = acc[mi][nj][r2] + bv;
        }
    }
}

// ---------------- launch ----------------

extern "C" void kernel_launch(void* const* d_in, const int* in_sizes, int n_in,
                              void* d_out, int out_size, void* d_ws, size_t ws_size,
                              hipStream_t stream) {
    const float* x      = (const float*)d_in[0];
    const int*   wq     = (const int*)d_in[1];
    const float* scales = (const float*)d_in[2];
    const float* bias   = (const float*)d_in[3];
    float*       out    = (float*)d_out;

    // Shapes: weight_q is [N, K] with N = |bias|; x is [M, K] flattened.
    const long N = (long)in_sizes[3];
    const long K = (long)in_sizes[1] / N;          // 67108864 / 16384 = 4096
    const long M = (long)in_sizes[0] / K;          // 16777216 / 4096  = 4096

    const size_t needW = (size_t)N * K * sizeof(short);
    const size_t needX = (size_t)M * K * sizeof(short);

    short* Wb = (short*)d_ws;
    short* Xb = Wb + (size_t)N * K;

    const bool preB = (d_ws != nullptr) && ws_size >= needW;
    const bool preA = preB && ws_size >= (needW + needX);

    if (preB) {
        long t8 = N * K / 8;
        prepack_w_kernel<<<dim3((unsigned)((t8 + 255) / 256)), dim3(256), 0, stream>>>(
            wq, scales, Wb, t8);
    }
    if (preA) {
        long t8 = M * K / 8;
        prepack_x_kernel<<<dim3((unsigned)((t8 + 255) / 256)), dim3(256), 0, stream>>>(
            x, Xb, t8);
    }

    dim3 grid((unsigned)((M / 128) * (N / 128))), block(256);
    if (preA)
        gemm_kernel<true, true><<<grid, block, 0, stream>>>(x, wq, scales, bias, Xb, Wb,
                                                            out, (int)M, (int)N, (int)K);
    else if (preB)
        gemm_kernel<false, true><<<grid, block, 0, stream>>>(x, wq, scales, bias, Xb, Wb,
                                                             out, (int)M, (int)N, (int)K);
    else
        gemm_kernel<false, false><<<grid, block, 0, stream>>>(x, wq, scales, bias, Xb, Wb,
                                                              out, (int)M, (int)N, (int)K);
}

// Round 3
// 645.140 us; speedup vs baseline: 1.1938x; 1.1938x over previous
//
#include <hip/hip_runtime.h>
#include <hip/hip_bf16.h>

typedef __attribute__((ext_vector_type(8))) short short8;
typedef __attribute__((ext_vector_type(4))) float f32x4;

#define AS1 __attribute__((address_space(1)))
#define AS3 __attribute__((address_space(3)))

static __device__ __forceinline__ short f2bf(float f) {
    __hip_bfloat16 h = __float2bfloat16(f);
    union { __hip_bfloat16 h; short s; } u;
    u.h = h;
    return u.s;
}

// ---------------- prepack kernels (run every launch; deterministic) ----------------

__global__ __launch_bounds__(256) void prepack_w_kernel(const int* __restrict__ wq,
                                                        const float* __restrict__ scales,
                                                        short* __restrict__ Wb,
                                                        long total8) {
    long i = (long)blockIdx.x * 256 + threadIdx.x;
    if (i >= total8) return;
    const int4* p = (const int4*)wq + i * 2;
    int4 q0 = p[0], q1 = p[1];
    float s = scales[(i * 8) >> 5];
    short8 v;
    v[0] = f2bf((float)(q0.x - 128) * s);
    v[1] = f2bf((float)(q0.y - 128) * s);
    v[2] = f2bf((float)(q0.z - 128) * s);
    v[3] = f2bf((float)(q0.w - 128) * s);
    v[4] = f2bf((float)(q1.x - 128) * s);
    v[5] = f2bf((float)(q1.y - 128) * s);
    v[6] = f2bf((float)(q1.z - 128) * s);
    v[7] = f2bf((float)(q1.w - 128) * s);
    ((short8*)Wb)[i] = v;
}

__global__ __launch_bounds__(256) void prepack_x_kernel(const float* __restrict__ x,
                                                        short* __restrict__ Xb,
                                                        long total8) {
    long i = (long)blockIdx.x * 256 + threadIdx.x;
    if (i >= total8) return;
    const float4* p = (const float4*)x + i * 2;
    float4 f0 = p[0], f1 = p[1];
    short8 v;
    v[0] = f2bf(f0.x); v[1] = f2bf(f0.y); v[2] = f2bf(f0.z); v[3] = f2bf(f0.w);
    v[4] = f2bf(f1.x); v[5] = f2bf(f1.y); v[6] = f2bf(f1.z); v[7] = f2bf(f1.w);
    ((short8*)Xb)[i] = v;
}

// ---------------- 256x256 8-phase GEMM (prepacked bf16 inputs) ----------------
// 512 threads = 8 waves (2M x 4N), per-wave C = 128x64, BK=64.
// LDS: A/B each 2-parity x 2-half x (128 rows x 64 bf16) = 64 KB -> 128 KB total.
// Granule(16B) XOR swizzle: LDS slot s of row r holds global granule s^(r&7).
// Schedule per K-group t (4 phases): phase q reads A m={2q,2q+1}; B read fully at
// q=0 into registers (frees B slots of parity t after q0's trailing barrier).
// Staging: A0(t+1)@q0, A1(t+1)@q1, B0(t+2)@q2, B1(t+2)@q3; vmcnt(4) once per group.
__global__ __launch_bounds__(512, 2)
void gemm256_kernel(const float* __restrict__ bias,
                    const short* __restrict__ Xb, const short* __restrict__ Wb,
                    float* __restrict__ out, int M, int N, int K) {
    __shared__ alignas(16) short As[4 * 8192];  // [parity*2+half][128*64]
    __shared__ alignas(16) short Bs[4 * 8192];

    const int nM = M >> 8, nN = N >> 8;
    int bid = blockIdx.x;
    {
        int nwg = nM * nN;
        if ((nwg & 7) == 0) bid = (bid & 7) * (nwg >> 3) + (bid >> 3);  // XCD swizzle
    }
    int pm, pn;
    {
        const int G = 8;
        if ((nN % G) == 0) {
            int per = nM * G;
            int grp = bid / per, in = bid % per;
            pn = grp * G + (in % G);
            pm = in / G;
        } else { pn = bid % nN; pm = bid / nN; }
    }

    const int tid  = threadIdx.x;
    const int lane = tid & 63;
    const int wid  = tid >> 6;     // 0..7
    const int wm   = wid >> 2;     // 0..1  (A half)
    const int wn   = wid & 3;      // 0..3
    const int q4   = lane >> 4;
    const int l15  = lane & 15;
    const int lx   = lane & 7;

    const long bm = (long)pm << 8, bn = (long)pn << 8;
    const long Kl = K;
    const int  NT = K >> 6;

    // fragment-read bases (short indices), per parity
    int rdA[2], rdB[2];
#pragma unroll
    for (int p = 0; p < 2; ++p) {
        rdA[p] = (p * 2 + wm) * 8192 + l15 * 64;
        rdB[p] = (p * 2 + (wn >> 1)) * 8192 + ((wn & 1) * 64 + l15) * 64;
    }
    const int sg0 = ((0 * 4 + q4) ^ lx) * 8;
    const int sg1 = ((1 * 4 + q4) ^ lx) * 8;

    // staging: LDS chunk (shorts) and pre-swizzled global sources
    const int chnk    = wid * 1024;                    // issue j adds 512
    const int srowrel = wid * 16 + (lane >> 3);
    const int scol    = ((lane & 7) ^ (lane >> 3)) * 8;

    const short* aSrc[2][2];  // [half][issue]
    const short* bSrc[2][2];
#pragma unroll
    for (int H = 0; H < 2; ++H)
#pragma unroll
        for (int j = 0; j < 2; ++j) {
            aSrc[H][j] = Xb + (bm + H * 128 + srowrel + j * 8) * Kl + scol;
            bSrc[H][j] = Wb + (bn + H * 128 + srowrel + j * 8) * Kl + scol;
        }

#define STAGE_A(H, t1) { int p_ = (t1) & 1; long ko_ = (long)(t1) << 6;              \
    __builtin_amdgcn_global_load_lds((const AS1 void*)(aSrc[H][0] + ko_),            \
        (AS3 void*)&As[(p_ * 2 + (H)) * 8192 + chnk], 16, 0, 0);                     \
    __builtin_amdgcn_global_load_lds((const AS1 void*)(aSrc[H][1] + ko_),            \
        (AS3 void*)&As[(p_ * 2 + (H)) * 8192 + chnk + 512], 16, 0, 0); }
#define STAGE_B(H, t2) { int p_ = (t2) & 1; long ko_ = (long)(t2) << 6;              \
    __builtin_amdgcn_global_load_lds((const AS1 void*)(bSrc[H][0] + ko_),            \
        (AS3 void*)&Bs[(p_ * 2 + (H)) * 8192 + chnk], 16, 0, 0);                     \
    __builtin_amdgcn_global_load_lds((const AS1 void*)(bSrc[H][1] + ko_),            \
        (AS3 void*)&Bs[(p_ * 2 + (H)) * 8192 + chnk + 512], 16, 0, 0); }

    f32x4 acc[8][4];
#pragma unroll
    for (int m = 0; m < 8; ++m)
#pragma unroll
        for (int n = 0; n < 4; ++n) acc[m][n] = (f32x4){0.f, 0.f, 0.f, 0.f};

    short8 bfr[4][2];

    // ---- prologue: tile 0 fully + B halves of tile 1 ----
    STAGE_B(0, 0); STAGE_B(1, 0);
    STAGE_A(0, 0); STAGE_A(1, 0);
    if (NT > 1) {
        STAGE_B(0, 1); STAGE_B(1, 1);
        asm volatile("s_waitcnt vmcnt(4)" ::: "memory");
    } else {
        asm volatile("s_waitcnt vmcnt(0)" ::: "memory");
    }
    __builtin_amdgcn_s_barrier();

    for (int t = 0; t < NT; ++t) {
        const int par = t & 1;
        const int ra = rdA[par], rb = rdB[par];
        const bool s1 = (t + 1 < NT), s2 = (t + 2 < NT);

#pragma unroll
        for (int q = 0; q < 4; ++q) {
            short8 ak[2][2];
#pragma unroll
            for (int mi = 0; mi < 2; ++mi) {
                ak[mi][0] = *(const short8*)&As[ra + (2 * q + mi) * 1024 + sg0];
                ak[mi][1] = *(const short8*)&As[ra + (2 * q + mi) * 1024 + sg1];
            }
            if (q == 0) {
#pragma unroll
                for (int n = 0; n < 4; ++n) {
                    bfr[n][0] = *(const short8*)&Bs[rb + n * 1024 + sg0];
                    bfr[n][1] = *(const short8*)&Bs[rb + n * 1024 + sg1];
                }
            }
            // staging issues (wave-uniform predicates)
            if (q == 0) { if (s1) STAGE_A(0, t + 1); }
            else if (q == 1) { if (s1) STAGE_A(1, t + 1); }
            else if (q == 2) { if (s2) STAGE_B(0, t + 2); }
            else           { if (s2) STAGE_B(1, t + 2); }

            if (q == 0) asm volatile("s_waitcnt lgkmcnt(8)" ::: "memory");
            __builtin_amdgcn_s_barrier();
            asm volatile("s_waitcnt lgkmcnt(0)" ::: "memory");
            __builtin_amdgcn_sched_barrier(0);

            __builtin_amdgcn_s_setprio(1);
#pragma unroll
            for (int mi = 0; mi < 2; ++mi) {
#pragma unroll
                for (int n = 0; n < 4; ++n)
                    acc[2 * q + mi][n] = __builtin_amdgcn_mfma_f32_16x16x32_bf16(
                        ak[mi][0], bfr[n][0], acc[2 * q + mi][n], 0, 0, 0);
#pragma unroll
                for (int n = 0; n < 4; ++n)
                    acc[2 * q + mi][n] = __builtin_amdgcn_mfma_f32_16x16x32_bf16(
                        ak[mi][1], bfr[n][1], acc[2 * q + mi][n], 0, 0, 0);
            }
            __builtin_amdgcn_s_setprio(0);

            if (q == 3) {
                if (s2)      asm volatile("s_waitcnt vmcnt(4)" ::: "memory");
                else if (s1) asm volatile("s_waitcnt vmcnt(0)" ::: "memory");
            }
            __builtin_amdgcn_s_barrier();
        }
        __builtin_amdgcn_sched_barrier(0);  // pin staging below the group-end barrier
    }

    // ---- epilogue ----
#pragma unroll
    for (int n = 0; n < 4; ++n) {
        long col = bn + wn * 64 + n * 16 + l15;
        float bv = bias[col];
#pragma unroll
        for (int m = 0; m < 8; ++m) {
            long row = bm + wm * 128 + m * 16 + q4 * 4;
#pragma unroll
            for (int r = 0; r < 4; ++r)
                out[(row + r) * (long)N + col] = acc[m][n][r] + bv;
        }
    }
#undef STAGE_A
#undef STAGE_B
}

// ---------------- fallback 128x128 GEMM (handles fused / odd shapes) ----------------

template <bool PRE_A, bool PRE_B>
__global__ __launch_bounds__(256, 2)
void gemm_kernel(const float* __restrict__ x, const int* __restrict__ wq,
                 const float* __restrict__ scales, const float* __restrict__ bias,
                 const short* __restrict__ Xb, const short* __restrict__ Wb,
                 float* __restrict__ out, int M, int N, int K) {
    constexpr int BM = 128, BN = 128, BK = 64;
    __shared__ alignas(16) short As[BM * BK];
    __shared__ alignas(16) short Bs[BN * BK];

    const int nM = M / BM, nN = N / BN;
    int bid = blockIdx.x;
    int pm, pn;
    const int G = 8;
    if ((nN % G) == 0) {
        int per = nM * G;
        int grp = bid / per;
        int in  = bid % per;
        pn = grp * G + (in % G);
        pm = in / G;
    } else {
        pn = bid % nN;
        pm = bid / nN;
    }

    const int tid  = threadIdx.x;
    const int lane = tid & 63;
    const int wv   = tid >> 6;
    const int wm   = (wv >> 1) * 64;
    const int wn   = (wv & 1) * 64;
    const int q    = lane >> 4;
    const int l15  = lane & 15;
    const int sxor = lane & 7;

    const long bm = (long)pm * BM, bn = (long)pn * BN;

    f32x4 acc[4][4];
#pragma unroll
    for (int i = 0; i < 4; ++i)
#pragma unroll
        for (int j = 0; j < 4; ++j) acc[i][j] = (f32x4){0.f, 0.f, 0.f, 0.f};

    const int srow = tid >> 3;
    const int scg  = tid & 7;

    const int sg0   = q ^ sxor;
    const int aOff0 = (wm + l15) * 64 + sg0 * 8;
    const int aOff1 = (wm + l15) * 64 + (sg0 ^ 4) * 8;
    const int bOff0 = (wn + l15) * 64 + sg0 * 8;
    const int bOff1 = (wn + l15) * 64 + (sg0 ^ 4) * 8;

    const int prRow  = lane >> 3;
    const int prGsrc = (lane & 7) ^ (lane >> 3);

    for (int k0 = 0; k0 < K; k0 += BK) {
        if constexpr (PRE_A) {
#pragma unroll
            for (int i = 0; i < 4; ++i) {
                int r = wv * 32 + i * 8 + prRow;
                const short* src = Xb + (bm + r) * (long)K + k0 + prGsrc * 8;
                __builtin_amdgcn_global_load_lds((const AS1 void*)src,
                                                 (AS3 void*)&As[(wv * 32 + i * 8) * 64],
                                                 16, 0, 0);
            }
        } else {
#pragma unroll
            for (int i = 0; i < 4; ++i) {
                int r = i * 32 + srow;
                const float4* p = (const float4*)(x + (bm + r) * (long)K + k0 + scg * 8);
                float4 f0 = p[0], f1 = p[1];
                short8 v;
                v[0] = f2bf(f0.x); v[1] = f2bf(f0.y); v[2] = f2bf(f0.z); v[3] = f2bf(f0.w);
                v[4] = f2bf(f1.x); v[5] = f2bf(f1.y); v[6] = f2bf(f1.z); v[7] = f2bf(f1.w);
                int sg = scg ^ (r & 7);
                *(short8*)&As[r * 64 + sg * 8] = v;
            }
        }
        if constexpr (PRE_B) {
#pragma unroll
            for (int i = 0; i < 4; ++i) {
                int r = wv * 32 + i * 8 + prRow;
                const short* src = Wb + (bn + r) * (long)K + k0 + prGsrc * 8;
                __builtin_amdgcn_global_load_lds((const AS1 void*)src,
                                                 (AS3 void*)&Bs[(wv * 32 + i * 8) * 64],
                                                 16, 0, 0);
            }
        } else {
#pragma unroll
            for (int i = 0; i < 4; ++i) {
                int r = i * 32 + srow;
                const int4* p = (const int4*)(wq + (bn + r) * (long)K + k0 + scg * 8);
                int4 q0 = p[0], q1 = p[1];
                float s = scales[(bn + r) * (long)(K >> 5) + ((k0 + scg * 8) >> 5)];
                short8 v;
                v[0] = f2bf((float)(q0.x - 128) * s);
                v[1] = f2bf((float)(q0.y - 128) * s);
                v[2] = f2bf((float)(q0.z - 128) * s);
                v[3] = f2bf((float)(q0.w - 128) * s);
                v[4] = f2bf((float)(q1.x - 128) * s);
                v[5] = f2bf((float)(q1.y - 128) * s);
                v[6] = f2bf((float)(q1.z - 128) * s);
                v[7] = f2bf((float)(q1.w - 128) * s);
                int sg = scg ^ (r & 7);
                *(short8*)&Bs[r * 64 + sg * 8] = v;
            }
        }
        __syncthreads();

#pragma unroll
        for (int kk = 0; kk < 2; ++kk) {
            short8 a[4], b[4];
            const int aBase = kk ? aOff1 : aOff0;
            const int bBase = kk ? bOff1 : bOff0;
#pragma unroll
            for (int mi = 0; mi < 4; ++mi) a[mi] = *(const short8*)&As[aBase + mi * 16 * 64];
#pragma unroll
            for (int nj = 0; nj < 4; ++nj) b[nj] = *(const short8*)&Bs[bBase + nj * 16 * 64];
#pragma unroll
            for (int mi = 0; mi < 4; ++mi)
#pragma unroll
                for (int nj = 0; nj < 4; ++nj)
                    acc[mi][nj] = __builtin_amdgcn_mfma_f32_16x16x32_bf16(
                        a[mi], b[nj], acc[mi][nj], 0, 0, 0);
        }
        __syncthreads();
    }

#pragma unroll
    for (int nj = 0; nj < 4; ++nj) {
        long col = bn + wn + nj * 16 + l15;
        float bv = bias[col];
#pragma unroll
        for (int mi = 0; mi < 4; ++mi) {
            long row = bm + wm + mi * 16 + q * 4;
#pragma unroll
            for (int r2 = 0; r2 < 4; ++r2)
                out[(row + r2) * (long)N + col] = acc[mi][nj][r2] + bv;
        }
    }
}

// ---------------- launch ----------------

extern "C" void kernel_launch(void* const* d_in, const int* in_sizes, int n_in,
                              void* d_out, int out_size, void* d_ws, size_t ws_size,
                              hipStream_t stream) {
    const float* x      = (const float*)d_in[0];
    const int*   wq     = (const int*)d_in[1];
    const float* scales = (const float*)d_in[2];
    const float* bias   = (const float*)d_in[3];
    float*       out    = (float*)d_out;

    const long N = (long)in_sizes[3];
    const long K = (long)in_sizes[1] / N;
    const long M = (long)in_sizes[0] / K;

    const size_t needW = (size_t)N * K * sizeof(short);
    const size_t needX = (size_t)M * K * sizeof(short);

    short* Wb = (short*)d_ws;
    short* Xb = Wb + (size_t)N * K;

    const bool preB = (d_ws != nullptr) && ws_size >= needW;
    const bool preA = preB && ws_size >= (needW + needX);

    if (preB) {
        long t8 = N * K / 8;
        prepack_w_kernel<<<dim3((unsigned)((t8 + 255) / 256)), dim3(256), 0, stream>>>(
            wq, scales, Wb, t8);
    }
    if (preA) {
        long t8 = M * K / 8;
        prepack_x_kernel<<<dim3((unsigned)((t8 + 255) / 256)), dim3(256), 0, stream>>>(
            x, Xb, t8);
    }

    const bool big = preA && (M % 256 == 0) && (N % 256 == 0) && (K % 64 == 0) && (K / 64 >= 2);

    if (big) {
        dim3 grid((unsigned)((M / 256) * (N / 256))), block(512);
        gemm256_kernel<<<grid, block, 0, stream>>>(bias, Xb, Wb, out, (int)M, (int)N, (int)K);
    } else {
        dim3 grid((unsigned)((M / 128) * (N / 128))), block(256);
        if (preA)
            gemm_kernel<true, true><<<grid, block, 0, stream>>>(x, wq, scales, bias, Xb, Wb,
                                                                out, (int)M, (int)N, (int)K);
        else if (preB)
            gemm_kernel<false, true><<<grid, block, 0, stream>>>(x, wq, scales, bias, Xb, Wb,
                                                                 out, (int)M, (int)N, (int)K);
        else
            gemm_kernel<false, false><<<grid, block, 0, stream>>>(x, wq, scales, bias, Xb, Wb,
                                                                  out, (int)M, (int)N, (int)K);
    }
}